// Round 1
// baseline (218.546 us; speedup 1.0000x reference)
//
#include <hip/hip_runtime.h>
#include <math.h>

// Problem sizes (fixed by the reference)
constexpr int B_ = 4, S_ = 1024, E_ = 128, H_ = 16, DK_ = 8, F_ = 512;
constexpr int R_ = B_ * S_; // 4096 token rows
#define EPSV 1e-5f

// Workspace layout (float offsets). x1 reuses qc's region (qc dead after attn).
constexpr int OFF_WQT  = 0;
constexpr int OFF_WOT  = OFF_WQT + E_ * E_;   // 16384
constexpr int OFF_W2T  = OFF_WOT + E_ * E_;   // 32768
constexpr int OFF_QC   = OFF_W2T + F_ * E_;   // 98304
constexpr int OFF_X1   = OFF_QC;              // reuse (qc consumed by k_attn)
constexpr int OFF_CTX  = OFF_QC  + R_ * E_;   // 622592
constexpr int OFF_QOUT = OFF_CTX + R_ * E_;   // 1146880
// total ws need: (1146880 + R_*8) * 4 B ≈ 4.6 MB

// ---------------------------------------------------------------- transpose
__global__ __launch_bounds__(256) void k_transpose(const float* __restrict__ Wq,
                                                   const float* __restrict__ Wo,
                                                   const float* __restrict__ W2,
                                                   float* __restrict__ ws) {
    int idx = blockIdx.x * 256 + threadIdx.x;
    if (idx < 16384) {
        int k = idx >> 7, e = idx & 127;
        ws[OFF_WQT + idx] = Wq[e * E_ + k];
    } else if (idx < 32768) {
        int j = idx - 16384;
        int k = j >> 7, e = j & 127;
        ws[OFF_WOT + j] = Wo[e * E_ + k];
    } else if (idx < 98304) {
        int j = idx - 32768;
        int f = j >> 7, e = j & 127;
        ws[OFF_W2T + j] = W2[e * F_ + f];
    }
}

// ------------------------------------------------- q projection + cos(+rx)
// out layout: qc[((b*H + h)*S + s)*DK + d]
__global__ __launch_bounds__(256) void k_qproj(const float* __restrict__ x,
                                               const float* __restrict__ bq,
                                               const float* __restrict__ rx,
                                               const float* __restrict__ WqT,
                                               float* __restrict__ qc) {
    __shared__ __attribute__((aligned(16))) float xs[16][128];
    const int tid = threadIdx.x;
    const int row0 = blockIdx.x * 16;
    {
        const float4* src = (const float4*)(x + row0 * E_);
        float4* dst = (float4*)&xs[0][0];
        dst[tid] = src[tid];
        dst[tid + 256] = src[tid + 256];
    }
    __syncthreads();
    const int cg = tid & 31, rg = tid >> 5;
    const int c0 = cg * 4;
    const int ra = rg * 2, rb = ra + 1;
    float a0x = 0, a0y = 0, a0z = 0, a0w = 0;
    float a1x = 0, a1y = 0, a1z = 0, a1w = 0;
#pragma unroll 4
    for (int k = 0; k < E_; ++k) {
        const float4 w = *(const float4*)(WqT + k * E_ + c0);
        const float u = xs[ra][k], v = xs[rb][k];
        a0x = fmaf(u, w.x, a0x); a0y = fmaf(u, w.y, a0y);
        a0z = fmaf(u, w.z, a0z); a0w = fmaf(u, w.w, a0w);
        a1x = fmaf(v, w.x, a1x); a1y = fmaf(v, w.y, a1y);
        a1z = fmaf(v, w.z, a1z); a1w = fmaf(v, w.w, a1w);
    }
    const float4 bv = *(const float4*)(bq + c0);
    const float4 rv = *(const float4*)(rx + c0);
    const int h = c0 >> 3, d0 = c0 & 7;
    {
        const int r = row0 + ra;
        const int b = r >> 10, s = r & 1023;
        float4 o;
        o.x = cosf(a0x + bv.x + rv.x);
        o.y = cosf(a0y + bv.y + rv.y);
        o.z = cosf(a0z + bv.z + rv.z);
        o.w = cosf(a0w + bv.w + rv.w);
        *(float4*)(qc + (((b * H_ + h) * S_ + s) * DK_ + d0)) = o;
    }
    {
        const int r = row0 + rb;
        const int b = r >> 10, s = r & 1023;
        float4 o;
        o.x = cosf(a1x + bv.x + rv.x);
        o.y = cosf(a1y + bv.y + rv.y);
        o.z = cosf(a1z + bv.z + rv.z);
        o.w = cosf(a1w + bv.w + rv.w);
        *(float4*)(qc + (((b * H_ + h) * S_ + s) * DK_ + d0)) = o;
    }
}

// ---------------------------------------------------------------- attention
// Bounded scores (|dot/sqrt(8)| <= 2.829) -> softmax without max subtraction.
// grid = 64 (b,h) * 4 q-tiles; block = 256 threads, 1 query/thread.
// ctx written in [B,S,E] layout (e = h*8+d).
__global__ __launch_bounds__(256) void k_attn(const float* __restrict__ qc,
                                              float* __restrict__ ctx) {
    __shared__ __attribute__((aligned(16))) float Ksh[S_ * DK_]; // 32 KB
    const int tid = threadIdx.x;
    const int bh = blockIdx.x >> 2;
    const int qt = blockIdx.x & 3;
    const float* kbase = qc + bh * (S_ * DK_);
    {
        const float4* src = (const float4*)kbase;
        float4* dst = (float4*)Ksh;
#pragma unroll
        for (int i = 0; i < 8; ++i) dst[i * 256 + tid] = src[i * 256 + tid];
    }
    __syncthreads();
    const int s0 = qt * 256 + tid;
    const float4 qa = *(const float4*)(kbase + s0 * DK_);
    const float4 qb = *(const float4*)(kbase + s0 * DK_ + 4);
    float ax = 0, ay = 0, az = 0, aw = 0;
    float bx = 0, by = 0, bz = 0, bw = 0;
    float lsum = 0.f;
#pragma unroll 4
    for (int t = 0; t < S_; ++t) {
        const float4 ka = *(const float4*)(Ksh + t * 8);
        const float4 kb = *(const float4*)(Ksh + t * 8 + 4);
        float d1 = fmaf(qa.x, ka.x, qa.y * ka.y);
        float d2 = fmaf(qa.z, ka.z, qa.w * ka.w);
        float d3 = fmaf(qb.x, kb.x, qb.y * kb.y);
        float d4 = fmaf(qb.z, kb.z, qb.w * kb.w);
        const float dot = (d1 + d2) + (d3 + d4);
        const float p = __expf(dot * 0.35355339059327373f);
        lsum += p;
        ax = fmaf(p, ka.x, ax); ay = fmaf(p, ka.y, ay);
        az = fmaf(p, ka.z, az); aw = fmaf(p, ka.w, aw);
        bx = fmaf(p, kb.x, bx); by = fmaf(p, kb.y, by);
        bz = fmaf(p, kb.z, bz); bw = fmaf(p, kb.w, bw);
    }
    const float inv = 1.0f / lsum;
    const int b = bh >> 4, h = bh & 15;
    float* dst = ctx + ((b * S_ + s0) * E_ + h * DK_);
    float4 o1, o2;
    o1.x = ax * inv; o1.y = ay * inv; o1.z = az * inv; o1.w = aw * inv;
    o2.x = bx * inv; o2.y = by * inv; o2.z = bz * inv; o2.w = bw * inv;
    *(float4*)dst = o1;
    *(float4*)(dst + 4) = o2;
}

// ----------------------------------- ctx@Wo^T + bo + x -> LN1 -> x1, qout
__global__ __launch_bounds__(256) void k_oproj_ln1(const float* __restrict__ ctx,
                                                   const float* __restrict__ WoT,
                                                   const float* __restrict__ bo,
                                                   const float* __restrict__ x,
                                                   const float* __restrict__ g1,
                                                   const float* __restrict__ bln1,
                                                   const float* __restrict__ ry,
                                                   float* __restrict__ x1,
                                                   float* __restrict__ qout) {
    __shared__ __attribute__((aligned(16))) float cs[16][128];
    const int tid = threadIdx.x;
    const int row0 = blockIdx.x * 16;
    {
        const float4* src = (const float4*)(ctx + row0 * E_);
        float4* dst = (float4*)&cs[0][0];
        dst[tid] = src[tid];
        dst[tid + 256] = src[tid + 256];
    }
    __syncthreads();
    const int cg = tid & 31, rg = tid >> 5;
    const int c0 = cg * 4;
    const int ra = rg * 2, rb = ra + 1;
    float a0x = 0, a0y = 0, a0z = 0, a0w = 0;
    float a1x = 0, a1y = 0, a1z = 0, a1w = 0;
#pragma unroll 4
    for (int k = 0; k < E_; ++k) {
        const float4 w = *(const float4*)(WoT + k * E_ + c0);
        const float u = cs[ra][k], v = cs[rb][k];
        a0x = fmaf(u, w.x, a0x); a0y = fmaf(u, w.y, a0y);
        a0z = fmaf(u, w.z, a0z); a0w = fmaf(u, w.w, a0w);
        a1x = fmaf(v, w.x, a1x); a1y = fmaf(v, w.y, a1y);
        a1z = fmaf(v, w.z, a1z); a1w = fmaf(v, w.w, a1w);
    }
    const float4 bv = *(const float4*)(bo + c0);
    const int gra = row0 + ra, grb = row0 + rb;
    const float4 xa = *(const float4*)(x + gra * E_ + c0);
    const float4 xb = *(const float4*)(x + grb * E_ + c0);
    float y0x = a0x + bv.x + xa.x, y0y = a0y + bv.y + xa.y;
    float y0z = a0z + bv.z + xa.z, y0w = a0w + bv.w + xa.w;
    float y1x = a1x + bv.x + xb.x, y1y = a1y + bv.y + xb.y;
    float y1z = a1z + bv.z + xb.z, y1w = a1w + bv.w + xb.w;
    // LN reduce across the 32 lanes (one 32-lane group per row pair)
    float s0 = (y0x + y0y) + (y0z + y0w);
    float q0 = fmaf(y0x, y0x, y0y * y0y) + fmaf(y0z, y0z, y0w * y0w);
    float s1 = (y1x + y1y) + (y1z + y1w);
    float q1 = fmaf(y1x, y1x, y1y * y1y) + fmaf(y1z, y1z, y1w * y1w);
#pragma unroll
    for (int m = 1; m < 32; m <<= 1) {
        s0 += __shfl_xor(s0, m);
        q0 += __shfl_xor(q0, m);
        s1 += __shfl_xor(s1, m);
        q1 += __shfl_xor(q1, m);
    }
    const float mu0 = s0 * (1.0f / 128.0f);
    const float var0 = q0 * (1.0f / 128.0f) - mu0 * mu0;
    const float is0 = rsqrtf(var0 + EPSV);
    const float mu1 = s1 * (1.0f / 128.0f);
    const float var1 = q1 * (1.0f / 128.0f) - mu1 * mu1;
    const float is1 = rsqrtf(var1 + EPSV);
    const float4 gv = *(const float4*)(g1 + c0);
    const float4 lb = *(const float4*)(bln1 + c0);
    float4 o0, o1;
    o0.x = (y0x - mu0) * is0 * gv.x + lb.x;
    o0.y = (y0y - mu0) * is0 * gv.y + lb.y;
    o0.z = (y0z - mu0) * is0 * gv.z + lb.z;
    o0.w = (y0w - mu0) * is0 * gv.w + lb.w;
    o1.x = (y1x - mu1) * is1 * gv.x + lb.x;
    o1.y = (y1y - mu1) * is1 * gv.y + lb.y;
    o1.z = (y1z - mu1) * is1 * gv.z + lb.z;
    o1.w = (y1w - mu1) * is1 * gv.w + lb.w;
    *(float4*)(x1 + gra * E_ + c0) = o0;
    *(float4*)(x1 + grb * E_ + c0) = o1;
    if (c0 < 8) {
        float4 cr;
        cr.x = cosf(ry[c0 + 0]); cr.y = cosf(ry[c0 + 1]);
        cr.z = cosf(ry[c0 + 2]); cr.w = cosf(ry[c0 + 3]);
        float4 qo0, qo1;
        qo0.x = cosf(o0.x) * cr.x; qo0.y = cosf(o0.y) * cr.y;
        qo0.z = cosf(o0.z) * cr.z; qo0.w = cosf(o0.w) * cr.w;
        qo1.x = cosf(o1.x) * cr.x; qo1.y = cosf(o1.y) * cr.y;
        qo1.z = cosf(o1.z) * cr.z; qo1.w = cosf(o1.w) * cr.w;
        *(float4*)(qout + gra * 8 + c0) = qo0;
        *(float4*)(qout + grb * 8 + c0) = qo1;
    }
}

// ------------------------- FFN (relu(qout@W1^T+b1)@W2^T+b2) + res + LN2
__global__ __launch_bounds__(256) void k_ffn_ln2(const float* __restrict__ qout,
                                                 const float* __restrict__ W1,
                                                 const float* __restrict__ b1,
                                                 const float* __restrict__ W2T,
                                                 const float* __restrict__ b2,
                                                 const float* __restrict__ x1,
                                                 const float* __restrict__ g2,
                                                 const float* __restrict__ bln2,
                                                 float* __restrict__ out) {
    __shared__ __attribute__((aligned(16))) float qs[16][8];
    __shared__ __attribute__((aligned(16))) float h1[16][512]; // 32 KB
    const int tid = threadIdx.x;
    const int row0 = blockIdx.x * 16;
    if (tid < 32) {
        ((float4*)&qs[0][0])[tid] = ((const float4*)(qout + row0 * 8))[tid];
    }
    __syncthreads();
#pragma unroll 4
    for (int i = 0; i < 32; ++i) {
        const int idx = i * 256 + tid;
        const int r = idx >> 9, f = idx & 511;
        const float4 wa = *(const float4*)(W1 + f * 8);
        const float4 wb = *(const float4*)(W1 + f * 8 + 4);
        const float4 qa = *(const float4*)&qs[r][0];
        const float4 qb = *(const float4*)&qs[r][4];
        float v = b1[f];
        v = fmaf(qa.x, wa.x, v); v = fmaf(qa.y, wa.y, v);
        v = fmaf(qa.z, wa.z, v); v = fmaf(qa.w, wa.w, v);
        v = fmaf(qb.x, wb.x, v); v = fmaf(qb.y, wb.y, v);
        v = fmaf(qb.z, wb.z, v); v = fmaf(qb.w, wb.w, v);
        h1[r][f] = fmaxf(v, 0.0f);
    }
    __syncthreads();
    const int cg = tid & 31, rg = tid >> 5;
    const int c0 = cg * 4;
    const int ra = rg * 2, rb = ra + 1;
    float a0x = 0, a0y = 0, a0z = 0, a0w = 0;
    float a1x = 0, a1y = 0, a1z = 0, a1w = 0;
#pragma unroll 4
    for (int f = 0; f < F_; ++f) {
        const float4 w = *(const float4*)(W2T + f * E_ + c0);
        const float u = h1[ra][f], v = h1[rb][f];
        a0x = fmaf(u, w.x, a0x); a0y = fmaf(u, w.y, a0y);
        a0z = fmaf(u, w.z, a0z); a0w = fmaf(u, w.w, a0w);
        a1x = fmaf(v, w.x, a1x); a1y = fmaf(v, w.y, a1y);
        a1z = fmaf(v, w.z, a1z); a1w = fmaf(v, w.w, a1w);
    }
    const float4 bv = *(const float4*)(b2 + c0);
    const int gra = row0 + ra, grb = row0 + rb;
    const float4 xa = *(const float4*)(x1 + gra * E_ + c0);
    const float4 xb = *(const float4*)(x1 + grb * E_ + c0);
    float y0x = a0x + bv.x + xa.x, y0y = a0y + bv.y + xa.y;
    float y0z = a0z + bv.z + xa.z, y0w = a0w + bv.w + xa.w;
    float y1x = a1x + bv.x + xb.x, y1y = a1y + bv.y + xb.y;
    float y1z = a1z + bv.z + xb.z, y1w = a1w + bv.w + xb.w;
    float s0 = (y0x + y0y) + (y0z + y0w);
    float q0 = fmaf(y0x, y0x, y0y * y0y) + fmaf(y0z, y0z, y0w * y0w);
    float s1 = (y1x + y1y) + (y1z + y1w);
    float q1 = fmaf(y1x, y1x, y1y * y1y) + fmaf(y1z, y1z, y1w * y1w);
#pragma unroll
    for (int m = 1; m < 32; m <<= 1) {
        s0 += __shfl_xor(s0, m);
        q0 += __shfl_xor(q0, m);
        s1 += __shfl_xor(s1, m);
        q1 += __shfl_xor(q1, m);
    }
    const float mu0 = s0 * (1.0f / 128.0f);
    const float var0 = q0 * (1.0f / 128.0f) - mu0 * mu0;
    const float is0 = rsqrtf(var0 + EPSV);
    const float mu1 = s1 * (1.0f / 128.0f);
    const float var1 = q1 * (1.0f / 128.0f) - mu1 * mu1;
    const float is1 = rsqrtf(var1 + EPSV);
    const float4 gv = *(const float4*)(g2 + c0);
    const float4 lb = *(const float4*)(bln2 + c0);
    float4 o0, o1;
    o0.x = (y0x - mu0) * is0 * gv.x + lb.x;
    o0.y = (y0y - mu0) * is0 * gv.y + lb.y;
    o0.z = (y0z - mu0) * is0 * gv.z + lb.z;
    o0.w = (y0w - mu0) * is0 * gv.w + lb.w;
    o1.x = (y1x - mu1) * is1 * gv.x + lb.x;
    o1.y = (y1y - mu1) * is1 * gv.y + lb.y;
    o1.z = (y1z - mu1) * is1 * gv.z + lb.z;
    o1.w = (y1w - mu1) * is1 * gv.w + lb.w;
    *(float4*)(out + gra * E_ + c0) = o0;
    *(float4*)(out + grb * E_ + c0) = o1;
}

extern "C" void kernel_launch(void* const* d_in, const int* in_sizes, int n_in,
                              void* d_out, int out_size, void* d_ws, size_t ws_size,
                              hipStream_t stream) {
    const float* x   = (const float*)d_in[0];
    const float* Wq  = (const float*)d_in[1];
    const float* bq  = (const float*)d_in[2];
    // d_in[3..6] = Wk, bk, Wv, bv : unused by the reference's output
    const float* rx  = (const float*)d_in[7];
    const float* Wo  = (const float*)d_in[8];
    const float* bo  = (const float*)d_in[9];
    const float* ry  = (const float*)d_in[10];
    const float* W1  = (const float*)d_in[11];
    const float* b1  = (const float*)d_in[12];
    const float* W2  = (const float*)d_in[13];
    const float* b2  = (const float*)d_in[14];
    const float* g1  = (const float*)d_in[15];
    const float* bl1 = (const float*)d_in[16];
    const float* g2  = (const float*)d_in[17];
    const float* bl2 = (const float*)d_in[18];
    float* ws  = (float*)d_ws;
    float* out = (float*)d_out;

    k_transpose<<<dim3(384), dim3(256), 0, stream>>>(Wq, Wo, W2, ws);
    k_qproj<<<dim3(R_ / 16), dim3(256), 0, stream>>>(x, bq, rx, ws + OFF_WQT, ws + OFF_QC);
    k_attn<<<dim3(B_ * H_ * 4), dim3(256), 0, stream>>>(ws + OFF_QC, ws + OFF_CTX);
    k_oproj_ln1<<<dim3(R_ / 16), dim3(256), 0, stream>>>(ws + OFF_CTX, ws + OFF_WOT, bo, x,
                                                         g1, bl1, ry,
                                                         ws + OFF_X1, ws + OFF_QOUT);
    k_ffn_ln2<<<dim3(R_ / 16), dim3(256), 0, stream>>>(ws + OFF_QOUT, W1, b1, ws + OFF_W2T,
                                                       b2, ws + OFF_X1, g2, bl2, out);
}